// Round 8
// baseline (636.449 us; speedup 1.0000x reference)
//
#include <hip/hip_runtime.h>
#include <math.h>

// ---------------------------------------------------------------------------
// OctreeAttention fused, round 8 = round 6 (PASSED, 467us) with k_fused's
// qkv GEMM re-decomposed for 2:1 MFMA:ds_read ratio:
//   waves own (wm: 32 rows) x (wn: 3 n-tiles); wn0={q0,q1,v0} wn1={k0,k1,v1}
//   (RoPE pairs stay within a wave). B-fragment LDS reads per head halve
//   (384 -> 192 wave-b128); MFMA count unchanged; attention verbatim.
// Micro-grafts: v_cvt_pk_bf16_f32 for q/k epilogue store (swap-canceling
// site), fractf, freqs pre-scaled by 1/2pi. k_prep/k_proj verbatim-green.
// ---------------------------------------------------------------------------

typedef float  float4v __attribute__((ext_vector_type(4)));
typedef short  bf16x8  __attribute__((ext_vector_type(8)));   // 8 bf16 = 4 VGPR
typedef unsigned short us4 __attribute__((ext_vector_type(4)));

#define SCALE_ 0.17677669529663687f   // 32^-0.5
#define INV2PI 0.15915494309189535f

__device__ __forceinline__ unsigned short f2bf(float x) {
  union { float f; unsigned u; } v; v.f = x;
  unsigned r = v.u + 0x7FFFu + ((v.u >> 16) & 1u);   // RNE
  return (unsigned short)(r >> 16);
}
__device__ __forceinline__ unsigned pack2bf(float lo, float hi) {
  return (unsigned)f2bf(lo) | ((unsigned)f2bf(hi) << 16);
}
// single-instruction pack: src0 -> bits[15:0], src1 -> bits[31:16]
__device__ __forceinline__ unsigned cvtpk(float lo, float hi) {
  unsigned r;
  asm("v_cvt_pk_bf16_f32 %0, %1, %2" : "=v"(r) : "v"(lo), "v"(hi));
  return r;
}
__device__ __forceinline__ float4v mfma16(bf16x8 a, bf16x8 b, float4v c) {
  return __builtin_amdgcn_mfma_f32_16x16x32_bf16(a, b, c, 0, 0, 0);
}
// XOR swizzle within 512B rows (A image + k_proj)
__device__ __forceinline__ int swz(int off) {
  return off ^ (((off >> 9) & 7) << 4);
}

// ------------------------------- K0: weights -------------------------------
// wqf: fragment-ordered bf16 blob. element(h,mat,s,g,col,e) =
//   h*24576 + mat*8192 + s*1024 + g*256 + col*8 + e
//   holds Wqkv[ci][co] with ci = s*32+g*8+e, co = mat*256+h*32+col.
// wproj_t[co][cpos] = bf16(Wproj[perm(cpos)][co]):
//   perm(cpos)=hh*32+f, hh=cpos>>5, ww=cpos&31, f=(ww&1)?16+(ww>>1):(ww>>1)
__global__ __launch_bounds__(256) void k_prep(const float* __restrict__ wqkv,
                                              const float* __restrict__ wproj,
                                              unsigned short* __restrict__ wqf,
                                              unsigned short* __restrict__ wp) {
  int tid = blockIdx.x * 256 + threadIdx.x;
  if (tid < 768 * 256) {
    int h  = tid / 24576;
    int r  = tid - h * 24576;
    int mat = r >> 13;
    int r2  = r & 8191;
    int s = r2 >> 10, g = (r2 >> 8) & 3, col = (r2 >> 3) & 31, e = r2 & 7;
    int ci = s * 32 + g * 8 + e;
    int co = mat * 256 + h * 32 + col;
    wqf[tid] = f2bf(wqkv[ci * 768 + co]);
  } else {
    int u = tid - 768 * 256;
    int co = u >> 8, cpos = u & 255;
    int hh = cpos >> 5, ww = cpos & 31;
    int f = (ww & 1) ? 16 + (ww >> 1) : (ww >> 1);
    wp[u] = f2bf(wproj[(hh * 32 + f) * 256 + co]);
  }
}

// ------------------------------- K1: fused ---------------------------------
// LDS (bytes):
//   B_s   @ 0      49152  3 frag-order weight tiles (q,k,v) 16KB each
//                         (PL aliases [0,10240) during attention; A-image
//                          (swz) aliases [0,65536) in the prologue)
//   QKq   @ 49152  10240  q [128 prow][80B] feature-pair interleaved
//   QKk   @ 59392  10240  k   "
//   VT    @ 69632   8704  V^T [32 f][272B], keys cpos-interleaved
//   ML    @ 78336    512  depths (prow order)
//   XYZ   @ 78848   1536  xyz f32 (row order)
//   F_s   @ 80384   1536  freqs f32, pre-scaled by 1/2pi
#define K1_LDS_BYTES 81920

__global__ __launch_bounds__(512, 4) void k_fused(
    const float* __restrict__ data, const float* __restrict__ xyz,
    const int* __restrict__ depth, const float* __restrict__ bqkv,
    const float* __restrict__ freqs, const unsigned short* __restrict__ wqf,
    unsigned short* __restrict__ aout /* d_out viewed as bf16 */) {
  extern __shared__ char smem[];
  const int b    = blockIdx.x;
  const int t    = threadIdx.x;
  const int lane = t & 63;
  const int w    = t >> 6;         // wave 0..7
  const int wm   = w >> 1;         // GEMM: rows [32wm,32wm+32); attn group d
  const int wn   = w & 1;          // GEMM: tile set {q-pair,v0} / {k-pair,v1};
                                   // attn: 16-row half within group
  const int g    = lane >> 4;      // 0..3
  const int l15  = lane & 15;

  // ---- stage small tables
  if (t < 128) ((int*)(smem + 78336))[t] =
      depth[b * 128 + ((t & 31) << 2) + (t >> 5)];          // prow order
  if (t < 384) ((float*)(smem + 78848))[t] = xyz[(size_t)b * 384 + t];
  if (t < 384) ((float*)(smem + 80384))[t] = freqs[t] * INV2PI;

  // ---- A restage: coalesced f32 loads -> swizzled bf16 [128][512B]
  {
    const float* dbase = data + (size_t)b * 32768;
#pragma unroll
    for (int i = 0; i < 16; ++i) {
      const int fidx = i * 512 + t;
      const float4v v4 = *reinterpret_cast<const float4v*>(dbase + fidx * 4);
      us4 pk;
      pk.x = f2bf(v4.x); pk.y = f2bf(v4.y); pk.z = f2bf(v4.z); pk.w = f2bf(v4.w);
      *reinterpret_cast<us4*>(smem + swz(fidx * 8)) = pk;
    }
  }
  __syncthreads();

  // ---- A fragments -> registers: 32 rows/wave (2 m-tiles), all heads reuse
  bf16x8 areg[2][8];
#pragma unroll
  for (int mt = 0; mt < 2; ++mt)
#pragma unroll
    for (int s = 0; s < 8; ++s)
      areg[mt][s] = *reinterpret_cast<const bf16x8*>(
          smem + swz((32 * wm + 16 * mt + l15) * 512 + s * 64 + g * 16));

  // ---- masks hoisted as floats (attention wave = (d=wm, half=wn))
  float maskf0[4], maskf1[4];
  {
    const int* ML = (const int*)(smem + 78336);
    const int mk0 = ML[32 * wm + l15];
    const int mk1 = ML[32 * wm + 16 + l15];
#pragma unroll
    for (int rr = 0; rr < 4; ++rr) {
      const int mq = ML[32 * wm + 16 * wn + 4 * g + rr];
      maskf0[rr] = (mq < mk0) ? -1000.f : 0.f;
      maskf1[rr] = (mq < mk1) ? -1000.f : 0.f;
    }
  }
  // ones B-fragment for softmax row-sum via MFMA
  bf16x8 ones;
#pragma unroll
  for (int j = 0; j < 8; ++j) ones[j] = (short)0x3F80;

  __syncthreads();   // A region free -> becomes weight-tile region

  const int bb    = g * 512 + l15 * 16;          // frag B read base
  const int mbase = wn ? 16384 : 0;              // q strips vs k strips
  const int voff  = 32768 + (wn ? 256 : 0);      // v0 vs v1 tile

#pragma unroll 1
  for (int h = 0; h < 8; ++h) {
    // ---- stage weight tiles: LINEAR copy of the 48KB frag-order blob
    {
      const char* wb = (const char*)wqf + (size_t)h * 49152 + t * 16;
      const bf16x8 s0 = *reinterpret_cast<const bf16x8*>(wb);
      const bf16x8 s1 = *reinterpret_cast<const bf16x8*>(wb + 8192);
      const bf16x8 s2 = *reinterpret_cast<const bf16x8*>(wb + 16384);
      const bf16x8 s3 = *reinterpret_cast<const bf16x8*>(wb + 24576);
      const bf16x8 s4 = *reinterpret_cast<const bf16x8*>(wb + 32768);
      const bf16x8 s5 = *reinterpret_cast<const bf16x8*>(wb + 40960);
      char* wd = smem + t * 16;
      *reinterpret_cast<bf16x8*>(wd)         = s0;
      *reinterpret_cast<bf16x8*>(wd + 8192)  = s1;
      *reinterpret_cast<bf16x8*>(wd + 16384) = s2;
      *reinterpret_cast<bf16x8*>(wd + 24576) = s3;
      *reinterpret_cast<bf16x8*>(wd + 32768) = s4;
      *reinterpret_cast<bf16x8*>(wd + 40960) = s5;
    }
    __syncthreads();

    // ---- GEMM: this wave's 3 n-tiles x 2 m-tiles (each B read feeds 2 MFMA)
    float4v a0[2], a1[2], av[2];
#pragma unroll
    for (int mt = 0; mt < 2; ++mt) {
      a0[mt] = (float4v){0.f, 0.f, 0.f, 0.f};
      a1[mt] = a0[mt];
      av[mt] = a0[mt];
    }
#pragma unroll
    for (int s = 0; s < 8; ++s) {
      const bf16x8 b0 = *reinterpret_cast<const bf16x8*>(smem + bb + s * 2048 + mbase);
      const bf16x8 b1 = *reinterpret_cast<const bf16x8*>(smem + bb + s * 2048 + mbase + 256);
      const bf16x8 bv = *reinterpret_cast<const bf16x8*>(smem + bb + s * 2048 + voff);
#pragma unroll
      for (int mt = 0; mt < 2; ++mt) {
        a0[mt] = mfma16(areg[mt][s], b0, a0[mt]);
        a1[mt] = mfma16(areg[mt][s], b1, a1[mt]);
        av[mt] = mfma16(areg[mt][s], bv, av[mt]);
      }
    }

    // ---- epilogue: bias + RoPE -> QKq/QKk ; v -> VT
    {
      const float bb0 = bqkv[wn * 256 + h * 32 + l15];
      const float bb1 = bqkv[wn * 256 + h * 32 + 16 + l15];
      const float bvv = bqkv[512 + h * 32 + 16 * wn + l15];
      const float* Fp = (const float*)(smem + 80384) + (h * 16 + l15) * 3;
      const float F0 = Fp[0], F1 = Fp[1], F2 = Fp[2];
      char* qkdst = smem + (wn ? 59392 : 49152);
      char* vdst  = smem + 69632 + (l15 + 16 * wn) * 272;
#pragma unroll
      for (int mt = 0; mt < 2; ++mt)
#pragma unroll
        for (int rr = 0; rr < 4; ++rr) {
          const int row  = 32 * wm + 16 * mt + 4 * g + rr;
          const int prow = ((row & 3) << 5) | (row >> 2);
          const float* xp = (const float*)(smem + 78848) + row * 3;
          const float th = xp[0] * F0 + xp[1] * F1 + xp[2] * F2;
          const float fr = __builtin_amdgcn_fractf(th);
          const float sn = __builtin_amdgcn_sinf(fr);
          const float cs = __builtin_amdgcn_cosf(fr);
          const float e0 = a0[mt][rr] + bb0;
          const float e1 = a1[mt][rr] + bb1;
          *reinterpret_cast<unsigned*>(qkdst + prow * 80 + 4 * l15) =
              cvtpk(e0 * cs - e1 * sn, e1 * cs + e0 * sn);
          const int kk = row >> 2, dd = row & 3;
          const int cpos = (kk < 16) ? (kk << 1) : (((kk - 16) << 1) | 1);
          *reinterpret_cast<unsigned short*>(vdst + (dd * 32 + cpos) * 2) =
              f2bf(av[mt][rr] + bvv);
        }
    }
    __syncthreads();

    // ---- attention: wave = (group wm, half wn), head h
    {
      const bf16x8 aq = *reinterpret_cast<const bf16x8*>(
          smem + 49152 + (32 * wm + 16 * wn + l15) * 80 + 16 * g);
      const bf16x8 bk0 = *reinterpret_cast<const bf16x8*>(
          smem + 59392 + (32 * wm + l15) * 80 + 16 * g);
      const bf16x8 bk1 = *reinterpret_cast<const bf16x8*>(
          smem + 59392 + (32 * wm + 16 + l15) * 80 + 16 * g);
      float4v s0 = {0.f,0.f,0.f,0.f}, s1 = s0;
      s0 = mfma16(aq, bk0, s0);
      s1 = mfma16(aq, bk1, s1);

      char* plw = smem + w * 1280;     // aliases dead q weight tile
#pragma unroll
      for (int rr = 0; rr < 4; ++rr) {
        // scores are O(0.2) -> exp without max-subtraction is safe
        const float p0 = __expf(s0[rr] * SCALE_ + maskf0[rr]);
        const float p1 = __expf(s1[rr] * SCALE_ + maskf1[rr]);
        *reinterpret_cast<unsigned*>(plw + (4 * g + rr) * 80 + 4 * l15) =
            pack2bf(p0, p1);
      }
      const bf16x8 ap = *reinterpret_cast<const bf16x8*>(plw + l15 * 80 + 16 * g);
      const bf16x8 bv0 = *reinterpret_cast<const bf16x8*>(
          smem + 69632 + l15 * 272 + wm * 64 + 16 * g);
      const bf16x8 bv1 = *reinterpret_cast<const bf16x8*>(
          smem + 69632 + (l15 + 16) * 272 + wm * 64 + 16 * g);
      float4v o0 = {0.f,0.f,0.f,0.f}, o1 = o0, osum = o0;
      osum = mfma16(ap, ones, osum);
      o0   = mfma16(ap, bv0, o0);
      o1   = mfma16(ap, bv1, o1);

      char* ob = (char*)aout + (size_t)b * 131072 + h * 64;
#pragma unroll
      for (int rr = 0; rr < 4; ++rr) {
        const float rs = __builtin_amdgcn_rcpf(osum[rr]);
        const int n_local = (16 * wn + 4 * g + rr) * 4 + wm;
        *reinterpret_cast<unsigned*>(ob + n_local * 512 + 4 * l15) =
            pack2bf(o0[rr] * rs, o1[rr] * rs);
      }
    }
    __syncthreads();
  }
}

// ------------------------------- K2: proj ----------------------------------
// verbatim-green (measured near its HBM floor)
#define K2_LDS_BYTES 81920

__global__ __launch_bounds__(512, 4) void k_proj(
    const unsigned short* ain,                       // d_out bf16 (aliases out!)
    const unsigned short* __restrict__ wproj_t,
    const float* __restrict__ bproj,
    float* out) {
  extern __shared__ char smem2[];
  const int b = blockIdx.x, t = threadIdx.x;
  const int lane = t & 63, w = t >> 6;
  const int g = lane >> 4, l15 = lane & 15;

  {
    const char* abase = (const char*)ain + (size_t)b * 131072;
    bf16x8 stg[8];
#pragma unroll
    for (int i = 0; i < 8; ++i)
      stg[i] = *reinterpret_cast<const bf16x8*>(abase + i * 8192 + t * 16);
#pragma unroll
    for (int i = 0; i < 8; ++i)
      *reinterpret_cast<bf16x8*>(smem2 + swz(i * 8192 + t * 16)) = stg[i];
  }
  __syncthreads();

  bf16x8 areg[8];
#pragma unroll
  for (int s = 0; s < 8; ++s)
    areg[s] = *reinterpret_cast<const bf16x8*>(
        smem2 + swz((16 * w + l15) * 512 + s * 64 + g * 16));

#pragma unroll 1
  for (int p = 0; p < 8; ++p) {
    const char* wb = (const char*)wproj_t + p * 16384;
    const bf16x8 s0 = *reinterpret_cast<const bf16x8*>(wb + t * 16);
    const bf16x8 s1 = *reinterpret_cast<const bf16x8*>(wb + 8192 + t * 16);
    __syncthreads();
    *reinterpret_cast<bf16x8*>(smem2 + 65536 + swz(t * 16)) = s0;
    *reinterpret_cast<bf16x8*>(smem2 + 65536 + swz(8192 + t * 16)) = s1;
    __syncthreads();

    float4v acc0 = {0.f,0.f,0.f,0.f}, acc1 = acc0;
#pragma unroll
    for (int s = 0; s < 8; ++s) {
      const int ko = s * 64 + g * 16;
      bf16x8 b0 = *reinterpret_cast<const bf16x8*>(smem2 + 65536 + swz(l15 * 512 + ko));
      bf16x8 b1 = *reinterpret_cast<const bf16x8*>(smem2 + 65536 + swz((l15 + 16) * 512 + ko));
      acc0 = mfma16(areg[s], b0, acc0);
      acc1 = mfma16(areg[s], b1, acc1);
    }
    const int col0 = 32 * p + l15, col1 = col0 + 16;
    const float bb0 = bproj[col0], bb1 = bproj[col1];
#pragma unroll
    for (int rr = 0; rr < 4; ++rr) {
      const int row = 16 * w + 4 * g + rr;
      out[((size_t)b * 128 + row) * 256 + col0] = acc0[rr] + bb0;
      out[((size_t)b * 128 + row) * 256 + col1] = acc1[rr] + bb1;
    }
  }
}

// ----------------------------- launch --------------------------------------
extern "C" void kernel_launch(void* const* d_in, const int* in_sizes, int n_in,
                              void* d_out, int out_size, void* d_ws, size_t ws_size,
                              hipStream_t stream) {
  const float* data  = (const float*)d_in[0];
  const float* xyz   = (const float*)d_in[1];
  const int*   depth = (const int*)d_in[2];
  const float* wqkv  = (const float*)d_in[3];
  const float* bqkv  = (const float*)d_in[4];
  const float* wproj = (const float*)d_in[5];
  const float* bproj = (const float*)d_in[6];
  const float* freqs = (const float*)d_in[7];

  unsigned short* wqkv_f  = (unsigned short*)d_ws;          // frag-ordered blob
  unsigned short* wproj_t = wqkv_f + 768 * 256;             // [co][cpos]

  (void)hipFuncSetAttribute(reinterpret_cast<const void*>(k_fused),
                            hipFuncAttributeMaxDynamicSharedMemorySize, K1_LDS_BYTES);
  (void)hipFuncSetAttribute(reinterpret_cast<const void*>(k_proj),
                            hipFuncAttributeMaxDynamicSharedMemorySize, K2_LDS_BYTES);

  k_prep<<<dim3(1024), dim3(256), 0, stream>>>(wqkv, wproj, wqkv_f, wproj_t);
  k_fused<<<dim3(3125), dim3(512), K1_LDS_BYTES, stream>>>(
      data, xyz, depth, bqkv, freqs, wqkv_f, (unsigned short*)d_out);
  k_proj<<<dim3(3125), dim3(512), K2_LDS_BYTES, stream>>>(
      (const unsigned short*)d_out, wproj_t, bproj, (float*)d_out);
}

// Round 9
// 627.834 us; speedup vs baseline: 1.0137x; 1.0137x over previous
//
#include <hip/hip_runtime.h>
#include <math.h>

// ---------------------------------------------------------------------------
// OctreeAttention fused, round 9 = round 8 (2:1 MFMA:ds_read decomposition,
// correctness-verified) with the spill removed:
//   - ALL weight staging via __builtin_amdgcn_global_load_lds width=16
//     (frag-ordered blobs are linear, wave-uniform-base + lane*16): frees the
//     24 staging VGPRs that pushed r8 over the 128-cap, kills staging VALU.
//   - k/v tiles of head h+1 prefetched DURING attention of head h (disjoint
//     LDS regions, race-checked); q tile at loop top. 3 barriers/head kept.
//   - k_proj: wproj re-emitted as frag blob -> linear gload staging,
//     base+immediate ds_reads, B(p+1) issued before the f32 stores.
// ---------------------------------------------------------------------------

typedef float  float4v __attribute__((ext_vector_type(4)));
typedef short  bf16x8  __attribute__((ext_vector_type(8)));   // 8 bf16 = 4 VGPR
typedef unsigned short us4 __attribute__((ext_vector_type(4)));

#define SCALE_ 0.17677669529663687f   // 32^-0.5
#define INV2PI 0.15915494309189535f

__device__ __forceinline__ unsigned short f2bf(float x) {
  union { float f; unsigned u; } v; v.f = x;
  unsigned r = v.u + 0x7FFFu + ((v.u >> 16) & 1u);   // RNE
  return (unsigned short)(r >> 16);
}
__device__ __forceinline__ unsigned pack2bf(float lo, float hi) {
  return (unsigned)f2bf(lo) | ((unsigned)f2bf(hi) << 16);
}
// single-instruction pack: src0 -> bits[15:0], src1 -> bits[31:16]
__device__ __forceinline__ unsigned cvtpk(float lo, float hi) {
  unsigned r;
  asm("v_cvt_pk_bf16_f32 %0, %1, %2" : "=v"(r) : "v"(lo), "v"(hi));
  return r;
}
__device__ __forceinline__ float4v mfma16(bf16x8 a, bf16x8 b, float4v c) {
  return __builtin_amdgcn_mfma_f32_16x16x32_bf16(a, b, c, 0, 0, 0);
}
// XOR swizzle within 512B rows (A images only; B paths are linear now)
__device__ __forceinline__ int swz(int off) {
  return off ^ (((off >> 9) & 7) << 4);
}
// async global->LDS, 16B per lane; lds dst is wave-uniform base (+lane*16 by HW)
__device__ __forceinline__ void gload16(const void* gsrc, char* ldst) {
  __builtin_amdgcn_global_load_lds(
      (const __attribute__((address_space(1))) unsigned int*)gsrc,
      (__attribute__((address_space(3))) unsigned int*)ldst, 16, 0, 0);
}

// ------------------------------- K0: weights -------------------------------
// wqf: fragment-ordered bf16 blob. element(h,mat,s,g,col,e) =
//   h*24576 + mat*8192 + s*1024 + g*256 + col*8 + e
//   holds Wqkv[ci][co], ci = s*32+g*8+e, co = mat*256+h*32+col.
// wpf: fragment-ordered wproj blob. element(p,s,g,col,e) =
//   p*8192 + s*1024 + g*256 + col*8 + e
//   holds Wproj[perm(cpos)][co], cpos = s*32+g*8+e, co = p*32+col,
//   perm(cpos)=hh*32+f, hh=cpos>>5, ww=cpos&31, f=(ww&1)?16+(ww>>1):(ww>>1)
__global__ __launch_bounds__(256) void k_prep(const float* __restrict__ wqkv,
                                              const float* __restrict__ wproj,
                                              unsigned short* __restrict__ wqf,
                                              unsigned short* __restrict__ wpf) {
  int tid = blockIdx.x * 256 + threadIdx.x;
  if (tid < 768 * 256) {
    int h  = tid / 24576;
    int r  = tid - h * 24576;
    int mat = r >> 13;
    int r2  = r & 8191;
    int s = r2 >> 10, g = (r2 >> 8) & 3, col = (r2 >> 3) & 31, e = r2 & 7;
    int ci = s * 32 + g * 8 + e;
    int co = mat * 256 + h * 32 + col;
    wqf[tid] = f2bf(wqkv[ci * 768 + co]);
  } else {
    int u = tid - 768 * 256;
    int p = u >> 13;
    int r2 = u & 8191;
    int s = r2 >> 10, g = (r2 >> 8) & 3, col = (r2 >> 3) & 31, e = r2 & 7;
    int cpos = s * 32 + g * 8 + e;
    int hh = cpos >> 5, ww = cpos & 31;
    int f = (ww & 1) ? 16 + (ww >> 1) : (ww >> 1);
    wpf[u] = f2bf(wproj[(hh * 32 + f) * 256 + p * 32 + col]);
  }
}

// ------------------------------- K1: fused ---------------------------------
// LDS (bytes):
//   B_s   @ 0      49152  3 frag-order weight tiles (q,k,v) 16KB each
//                         (PL aliases [0,10240) during attention; A-image
//                          (swz) aliases [0,65536) in the prologue)
//   QKq   @ 49152  10240  q [128 prow][80B] feature-pair interleaved
//   QKk   @ 59392  10240  k   "
//   VT    @ 69632   8704  V^T [32 f][272B], keys cpos-interleaved
//   ML    @ 78336    512  depths (prow order)
//   XYZ   @ 78848   1536  xyz f32 (row order)
//   F_s   @ 80384   1536  freqs f32, pre-scaled by 1/2pi
#define K1_LDS_BYTES 81920

__global__ __launch_bounds__(512, 4) void k_fused(
    const float* __restrict__ data, const float* __restrict__ xyz,
    const int* __restrict__ depth, const float* __restrict__ bqkv,
    const float* __restrict__ freqs, const unsigned short* __restrict__ wqf,
    unsigned short* __restrict__ aout /* d_out viewed as bf16 */) {
  extern __shared__ char smem[];
  const int b    = blockIdx.x;
  const int t    = threadIdx.x;
  const int lane = t & 63;
  const int w    = t >> 6;         // wave 0..7
  const int wm   = w >> 1;         // GEMM: rows [32wm,32wm+32); attn group d
  const int wn   = w & 1;          // GEMM: {q-pair,v0} / {k-pair,v1}; attn half
  const int g    = lane >> 4;      // 0..3
  const int l15  = lane & 15;

  // ---- stage small tables
  if (t < 128) ((int*)(smem + 78336))[t] =
      depth[b * 128 + ((t & 31) << 2) + (t >> 5)];          // prow order
  if (t < 384) ((float*)(smem + 78848))[t] = xyz[(size_t)b * 384 + t];
  if (t < 384) ((float*)(smem + 80384))[t] = freqs[t] * INV2PI;

  // ---- A restage: coalesced f32 loads -> swizzled bf16 [128][512B]
  {
    const float* dbase = data + (size_t)b * 32768;
#pragma unroll
    for (int i = 0; i < 16; ++i) {
      const int fidx = i * 512 + t;
      const float4v v4 = *reinterpret_cast<const float4v*>(dbase + fidx * 4);
      us4 pk;
      pk.x = f2bf(v4.x); pk.y = f2bf(v4.y); pk.z = f2bf(v4.z); pk.w = f2bf(v4.w);
      *reinterpret_cast<us4*>(smem + swz(fidx * 8)) = pk;
    }
  }
  __syncthreads();

  // ---- A fragments -> registers: 32 rows/wave (2 m-tiles), all heads reuse
  bf16x8 areg[2][8];
#pragma unroll
  for (int mt = 0; mt < 2; ++mt)
#pragma unroll
    for (int s = 0; s < 8; ++s)
      areg[mt][s] = *reinterpret_cast<const bf16x8*>(
          smem + swz((32 * wm + 16 * mt + l15) * 512 + s * 64 + g * 16));

  // ---- masks hoisted as floats (attention wave = (d=wm, half=wn))
  float maskf0[4], maskf1[4];
  {
    const int* ML = (const int*)(smem + 78336);
    const int mk0 = ML[32 * wm + l15];
    const int mk1 = ML[32 * wm + 16 + l15];
#pragma unroll
    for (int rr = 0; rr < 4; ++rr) {
      const int mq = ML[32 * wm + 16 * wn + 4 * g + rr];
      maskf0[rr] = (mq < mk0) ? -1000.f : 0.f;
      maskf1[rr] = (mq < mk1) ? -1000.f : 0.f;
    }
  }
  // ones B-fragment for softmax row-sum via MFMA
  bf16x8 ones;
#pragma unroll
  for (int j = 0; j < 8; ++j) ones[j] = (short)0x3F80;

  __syncthreads();   // A-image reads complete -> region becomes weight tiles

  const int wub   = (t >> 6) << 10;              // wave-uniform chunk base
  const int bb    = g * 512 + l15 * 16;          // frag B read base
  const int mbase = wn ? 16384 : 0;              // q strips vs k strips
  const int voff  = 32768 + (wn ? 256 : 0);      // v0 vs v1 tile
  const char* gblk = (const char*)wqf + t * 16;  // per-lane global base

  // ---- prologue prefetch: k,v tiles of head 0 (chunks 2..5)
#pragma unroll
  for (int j = 2; j < 6; ++j)
    gload16(gblk + j * 8192, smem + j * 8192 + wub);

#pragma unroll 1
  for (int h = 0; h < 8; ++h) {
    // ---- stage q tile of head h (chunks 0,1); k,v already in flight
    {
      const char* gh = gblk + (size_t)h * 49152;
      gload16(gh, smem + wub);
      gload16(gh + 8192, smem + 8192 + wub);
    }
    __syncthreads();   // drains vmcnt: all 6 chunks of B(h) landed

    // ---- GEMM: this wave's 3 n-tiles x 2 m-tiles (each B read feeds 2 MFMA)
    float4v a0[2], a1[2], av[2];
#pragma unroll
    for (int mt = 0; mt < 2; ++mt) {
      a0[mt] = (float4v){0.f, 0.f, 0.f, 0.f};
      a1[mt] = a0[mt];
      av[mt] = a0[mt];
    }
#pragma unroll
    for (int s = 0; s < 8; ++s) {
      const bf16x8 b0 = *reinterpret_cast<const bf16x8*>(smem + bb + s * 2048 + mbase);
      const bf16x8 b1 = *reinterpret_cast<const bf16x8*>(smem + bb + s * 2048 + mbase + 256);
      const bf16x8 bv = *reinterpret_cast<const bf16x8*>(smem + bb + s * 2048 + voff);
#pragma unroll
      for (int mt = 0; mt < 2; ++mt) {
        a0[mt] = mfma16(areg[mt][s], b0, a0[mt]);
        a1[mt] = mfma16(areg[mt][s], b1, a1[mt]);
        av[mt] = mfma16(areg[mt][s], bv, av[mt]);
      }
    }

    // ---- epilogue: bias + RoPE -> QKq/QKk ; v -> VT
    {
      const float bb0 = bqkv[wn * 256 + h * 32 + l15];
      const float bb1 = bqkv[wn * 256 + h * 32 + 16 + l15];
      const float bvv = bqkv[512 + h * 32 + 16 * wn + l15];
      const float* Fp = (const float*)(smem + 80384) + (h * 16 + l15) * 3;
      const float F0 = Fp[0], F1 = Fp[1], F2 = Fp[2];
      char* qkdst = smem + (wn ? 59392 : 49152);
      char* vdst  = smem + 69632 + (l15 + 16 * wn) * 272;
#pragma unroll
      for (int mt = 0; mt < 2; ++mt)
#pragma unroll
        for (int rr = 0; rr < 4; ++rr) {
          const int row  = 32 * wm + 16 * mt + 4 * g + rr;
          const int prow = ((row & 3) << 5) | (row >> 2);
          const float* xp = (const float*)(smem + 78848) + row * 3;
          const float th = xp[0] * F0 + xp[1] * F1 + xp[2] * F2;
          const float fr = __builtin_amdgcn_fractf(th);
          const float sn = __builtin_amdgcn_sinf(fr);
          const float cs = __builtin_amdgcn_cosf(fr);
          const float e0 = a0[mt][rr] + bb0;
          const float e1 = a1[mt][rr] + bb1;
          *reinterpret_cast<unsigned*>(qkdst + prow * 80 + 4 * l15) =
              cvtpk(e0 * cs - e1 * sn, e1 * cs + e0 * sn);
          const int kk = row >> 2, dd = row & 3;
          const int cpos = (kk < 16) ? (kk << 1) : (((kk - 16) << 1) | 1);
          *reinterpret_cast<unsigned short*>(vdst + (dd * 32 + cpos) * 2) =
              f2bf(av[mt][rr] + bvv);
        }
    }
    __syncthreads();   // QK/VT visible; all GEMM B-reads of head h complete

    // ---- prefetch k,v tiles of head h+1 (write [16384,49152): disjoint from
    //      PL [0,10240), QKq/QKk, VT — safe to be in flight during attention)
    if (h < 7) {
      const char* gn = gblk + (size_t)(h + 1) * 49152;
#pragma unroll
      for (int j = 2; j < 6; ++j)
        gload16(gn + j * 8192, smem + j * 8192 + wub);
    }

    // ---- attention: wave = (group wm, half wn), head h
    {
      const bf16x8 aq = *reinterpret_cast<const bf16x8*>(
          smem + 49152 + (32 * wm + 16 * wn + l15) * 80 + 16 * g);
      const bf16x8 bk0 = *reinterpret_cast<const bf16x8*>(
          smem + 59392 + (32 * wm + l15) * 80 + 16 * g);
      const bf16x8 bk1 = *reinterpret_cast<const bf16x8*>(
          smem + 59392 + (32 * wm + 16 + l15) * 80 + 16 * g);
      float4v s0 = {0.f,0.f,0.f,0.f}, s1 = s0;
      s0 = mfma16(aq, bk0, s0);
      s1 = mfma16(aq, bk1, s1);

      char* plw = smem + w * 1280;     // aliases dead q weight tile
#pragma unroll
      for (int rr = 0; rr < 4; ++rr) {
        // scores are O(0.2) -> exp without max-subtraction is safe
        const float p0 = __expf(s0[rr] * SCALE_ + maskf0[rr]);
        const float p1 = __expf(s1[rr] * SCALE_ + maskf1[rr]);
        *reinterpret_cast<unsigned*>(plw + (4 * g + rr) * 80 + 4 * l15) =
            pack2bf(p0, p1);
      }
      const bf16x8 ap = *reinterpret_cast<const bf16x8*>(plw + l15 * 80 + 16 * g);
      const bf16x8 bv0 = *reinterpret_cast<const bf16x8*>(
          smem + 69632 + l15 * 272 + wm * 64 + 16 * g);
      const bf16x8 bv1 = *reinterpret_cast<const bf16x8*>(
          smem + 69632 + (l15 + 16) * 272 + wm * 64 + 16 * g);
      float4v o0 = {0.f,0.f,0.f,0.f}, o1 = o0, osum = o0;
      osum = mfma16(ap, ones, osum);
      o0   = mfma16(ap, bv0, o0);
      o1   = mfma16(ap, bv1, o1);

      char* ob = (char*)aout + (size_t)b * 131072 + h * 64;
#pragma unroll
      for (int rr = 0; rr < 4; ++rr) {
        const float rs = __builtin_amdgcn_rcpf(osum[rr]);
        const int n_local = (16 * wn + 4 * g + rr) * 4 + wm;
        *reinterpret_cast<unsigned*>(ob + n_local * 512 + 4 * l15) =
            pack2bf(o0[rr] * rs, o1[rr] * rs);
      }
    }
    __syncthreads();   // PL/QK/VT reads done; q region reusable next iter
  }
}

// ------------------------------- K2: proj ----------------------------------
// A restage r7-verbatim (swz both sides); B via frag blob + global_load_lds.
#define K2_LDS_BYTES 81920

__global__ __launch_bounds__(512, 4) void k_proj(
    const unsigned short* ain,                       // d_out bf16 (aliases out!)
    const unsigned short* __restrict__ wpf,
    const float* __restrict__ bproj,
    float* out) {
  extern __shared__ char smem2[];
  const int b = blockIdx.x, t = threadIdx.x;
  const int lane = t & 63, w = t >> 6;
  const int g = lane >> 4, l15 = lane & 15;
  const int wub = (t >> 6) << 10;
  const char* gblk = (const char*)wpf + t * 16;

  {
    const char* abase = (const char*)ain + (size_t)b * 131072;
    bf16x8 stg[8];
#pragma unroll
    for (int i = 0; i < 8; ++i)
      stg[i] = *reinterpret_cast<const bf16x8*>(abase + i * 8192 + t * 16);
#pragma unroll
    for (int i = 0; i < 8; ++i)
      *reinterpret_cast<bf16x8*>(smem2 + swz(i * 8192 + t * 16)) = stg[i];
  }
  // issue B(0) staging (linear frag blob)
  gload16(gblk, smem2 + 65536 + wub);
  gload16(gblk + 8192, smem2 + 65536 + 8192 + wub);
  __syncthreads();   // A image + B(0) ready

  bf16x8 areg[8];
#pragma unroll
  for (int s = 0; s < 8; ++s)
    areg[s] = *reinterpret_cast<const bf16x8*>(
        smem2 + swz((16 * w + l15) * 512 + s * 64 + g * 16));

#pragma unroll 1
  for (int p = 0; p < 8; ++p) {
    float4v acc0 = {0.f,0.f,0.f,0.f}, acc1 = acc0;
#pragma unroll
    for (int s = 0; s < 8; ++s) {
      const bf16x8 b0 = *reinterpret_cast<const bf16x8*>(
          smem2 + 65536 + s * 2048 + g * 512 + l15 * 16);
      const bf16x8 b1 = *reinterpret_cast<const bf16x8*>(
          smem2 + 65536 + s * 2048 + g * 512 + l15 * 16 + 256);
      acc0 = mfma16(areg[s], b0, acc0);
      acc1 = mfma16(areg[s], b1, acc1);
    }
    __syncthreads();   // all waves done reading B(p)
    if (p < 7) {       // issue B(p+1); latency hides under the f32 stores
      const char* gn = gblk + (size_t)(p + 1) * 16384;
      gload16(gn, smem2 + 65536 + wub);
      gload16(gn + 8192, smem2 + 65536 + 8192 + wub);
    }
    const int col0 = 32 * p + l15, col1 = col0 + 16;
    const float bb0 = bproj[col0], bb1 = bproj[col1];
#pragma unroll
    for (int rr = 0; rr < 4; ++rr) {
      const int row = 16 * w + 4 * g + rr;
      out[((size_t)b * 128 + row) * 256 + col0] = acc0[rr] + bb0;
      out[((size_t)b * 128 + row) * 256 + col1] = acc1[rr] + bb1;
    }
    __syncthreads();   // drains vmcnt -> B(p+1) landed
  }
}

// ----------------------------- launch --------------------------------------
extern "C" void kernel_launch(void* const* d_in, const int* in_sizes, int n_in,
                              void* d_out, int out_size, void* d_ws, size_t ws_size,
                              hipStream_t stream) {
  const float* data  = (const float*)d_in[0];
  const float* xyz   = (const float*)d_in[1];
  const int*   depth = (const int*)d_in[2];
  const float* wqkv  = (const float*)d_in[3];
  const float* bqkv  = (const float*)d_in[4];
  const float* wproj = (const float*)d_in[5];
  const float* bproj = (const float*)d_in[6];
  const float* freqs = (const float*)d_in[7];

  unsigned short* wqkv_f  = (unsigned short*)d_ws;          // frag-ordered blob
  unsigned short* wproj_f = wqkv_f + 768 * 256;             // frag-ordered blob

  (void)hipFuncSetAttribute(reinterpret_cast<const void*>(k_fused),
                            hipFuncAttributeMaxDynamicSharedMemorySize, K1_LDS_BYTES);
  (void)hipFuncSetAttribute(reinterpret_cast<const void*>(k_proj),
                            hipFuncAttributeMaxDynamicSharedMemorySize, K2_LDS_BYTES);

  k_prep<<<dim3(1024), dim3(256), 0, stream>>>(wqkv, wproj, wqkv_f, wproj_f);
  k_fused<<<dim3(3125), dim3(512), K1_LDS_BYTES, stream>>>(
      data, xyz, depth, bqkv, freqs, wqkv_f, (unsigned short*)d_out);
  k_proj<<<dim3(3125), dim3(512), K2_LDS_BYTES, stream>>>(
      (const unsigned short*)d_out, wproj_f, bproj, (float*)d_out);
}

// Round 10
// 535.738 us; speedup vs baseline: 1.1880x; 1.1719x over previous
//
#include <hip/hip_runtime.h>
#include <math.h>

// ---------------------------------------------------------------------------
// OctreeAttention fused, round 10 = round 9 with ONE change:
//   k_fused __launch_bounds__(512,4) -> (512,2).
// Diagnosis r8/r9: under (512,4) the 128-unified-reg budget is split
// arch/accum by the backend; arch cap landed at 64 (= VGPR_Count both rounds),
// areg[2][8] alone fills it, temps spill to scratch (WRITE_SIZE 374MB vs
// 205MB real). (512,2) gives a 256-reg budget; expected landing ~100-120
// arch VGPRs, still <=128 so 2 blocks/CU (4 waves/SIMD) is preserved.
// Everything else verbatim from the green r9 kernel.
// ---------------------------------------------------------------------------

typedef float  float4v __attribute__((ext_vector_type(4)));
typedef short  bf16x8  __attribute__((ext_vector_type(8)));   // 8 bf16 = 4 VGPR
typedef unsigned short us4 __attribute__((ext_vector_type(4)));

#define SCALE_ 0.17677669529663687f   // 32^-0.5
#define INV2PI 0.15915494309189535f

__device__ __forceinline__ unsigned short f2bf(float x) {
  union { float f; unsigned u; } v; v.f = x;
  unsigned r = v.u + 0x7FFFu + ((v.u >> 16) & 1u);   // RNE
  return (unsigned short)(r >> 16);
}
__device__ __forceinline__ unsigned pack2bf(float lo, float hi) {
  return (unsigned)f2bf(lo) | ((unsigned)f2bf(hi) << 16);
}
// single-instruction pack: src0 -> bits[15:0], src1 -> bits[31:16]
__device__ __forceinline__ unsigned cvtpk(float lo, float hi) {
  unsigned r;
  asm("v_cvt_pk_bf16_f32 %0, %1, %2" : "=v"(r) : "v"(lo), "v"(hi));
  return r;
}
__device__ __forceinline__ float4v mfma16(bf16x8 a, bf16x8 b, float4v c) {
  return __builtin_amdgcn_mfma_f32_16x16x32_bf16(a, b, c, 0, 0, 0);
}
// XOR swizzle within 512B rows (A images only; B paths are linear)
__device__ __forceinline__ int swz(int off) {
  return off ^ (((off >> 9) & 7) << 4);
}
// async global->LDS, 16B per lane; lds dst is wave-uniform base (+lane*16 by HW)
__device__ __forceinline__ void gload16(const void* gsrc, char* ldst) {
  __builtin_amdgcn_global_load_lds(
      (const __attribute__((address_space(1))) unsigned int*)gsrc,
      (__attribute__((address_space(3))) unsigned int*)ldst, 16, 0, 0);
}

// ------------------------------- K0: weights -------------------------------
// wqf: fragment-ordered bf16 blob. element(h,mat,s,g,col,e) =
//   h*24576 + mat*8192 + s*1024 + g*256 + col*8 + e
//   holds Wqkv[ci][co], ci = s*32+g*8+e, co = mat*256+h*32+col.
// wpf: fragment-ordered wproj blob. element(p,s,g,col,e) =
//   p*8192 + s*1024 + g*256 + col*8 + e
//   holds Wproj[perm(cpos)][co], cpos = s*32+g*8+e, co = p*32+col,
//   perm(cpos)=hh*32+f, hh=cpos>>5, ww=cpos&31, f=(ww&1)?16+(ww>>1):(ww>>1)
__global__ __launch_bounds__(256) void k_prep(const float* __restrict__ wqkv,
                                              const float* __restrict__ wproj,
                                              unsigned short* __restrict__ wqf,
                                              unsigned short* __restrict__ wpf) {
  int tid = blockIdx.x * 256 + threadIdx.x;
  if (tid < 768 * 256) {
    int h  = tid / 24576;
    int r  = tid - h * 24576;
    int mat = r >> 13;
    int r2  = r & 8191;
    int s = r2 >> 10, g = (r2 >> 8) & 3, col = (r2 >> 3) & 31, e = r2 & 7;
    int ci = s * 32 + g * 8 + e;
    int co = mat * 256 + h * 32 + col;
    wqf[tid] = f2bf(wqkv[ci * 768 + co]);
  } else {
    int u = tid - 768 * 256;
    int p = u >> 13;
    int r2 = u & 8191;
    int s = r2 >> 10, g = (r2 >> 8) & 3, col = (r2 >> 3) & 31, e = r2 & 7;
    int cpos = s * 32 + g * 8 + e;
    int hh = cpos >> 5, ww = cpos & 31;
    int f = (ww & 1) ? 16 + (ww >> 1) : (ww >> 1);
    wpf[u] = f2bf(wproj[(hh * 32 + f) * 256 + p * 32 + col]);
  }
}

// ------------------------------- K1: fused ---------------------------------
// LDS (bytes):
//   B_s   @ 0      49152  3 frag-order weight tiles (q,k,v) 16KB each
//                         (PL aliases [0,10240) during attention; A-image
//                          (swz) aliases [0,65536) in the prologue)
//   QKq   @ 49152  10240  q [128 prow][80B] feature-pair interleaved
//   QKk   @ 59392  10240  k   "
//   VT    @ 69632   8704  V^T [32 f][272B], keys cpos-interleaved
//   ML    @ 78336    512  depths (prow order)
//   XYZ   @ 78848   1536  xyz f32 (row order)
//   F_s   @ 80384   1536  freqs f32, pre-scaled by 1/2pi
#define K1_LDS_BYTES 81920

__global__ __launch_bounds__(512, 2) void k_fused(
    const float* __restrict__ data, const float* __restrict__ xyz,
    const int* __restrict__ depth, const float* __restrict__ bqkv,
    const float* __restrict__ freqs, const unsigned short* __restrict__ wqf,
    unsigned short* __restrict__ aout /* d_out viewed as bf16 */) {
  extern __shared__ char smem[];
  const int b    = blockIdx.x;
  const int t    = threadIdx.x;
  const int lane = t & 63;
  const int w    = t >> 6;         // wave 0..7
  const int wm   = w >> 1;         // GEMM: rows [32wm,32wm+32); attn group d
  const int wn   = w & 1;          // GEMM: {q-pair,v0} / {k-pair,v1}; attn half
  const int g    = lane >> 4;      // 0..3
  const int l15  = lane & 15;

  // ---- stage small tables
  if (t < 128) ((int*)(smem + 78336))[t] =
      depth[b * 128 + ((t & 31) << 2) + (t >> 5)];          // prow order
  if (t < 384) ((float*)(smem + 78848))[t] = xyz[(size_t)b * 384 + t];
  if (t < 384) ((float*)(smem + 80384))[t] = freqs[t] * INV2PI;

  // ---- A restage: coalesced f32 loads -> swizzled bf16 [128][512B]
  {
    const float* dbase = data + (size_t)b * 32768;
#pragma unroll
    for (int i = 0; i < 16; ++i) {
      const int fidx = i * 512 + t;
      const float4v v4 = *reinterpret_cast<const float4v*>(dbase + fidx * 4);
      us4 pk;
      pk.x = f2bf(v4.x); pk.y = f2bf(v4.y); pk.z = f2bf(v4.z); pk.w = f2bf(v4.w);
      *reinterpret_cast<us4*>(smem + swz(fidx * 8)) = pk;
    }
  }
  __syncthreads();

  // ---- A fragments -> registers: 32 rows/wave (2 m-tiles), all heads reuse
  bf16x8 areg[2][8];
#pragma unroll
  for (int mt = 0; mt < 2; ++mt)
#pragma unroll
    for (int s = 0; s < 8; ++s)
      areg[mt][s] = *reinterpret_cast<const bf16x8*>(
          smem + swz((32 * wm + 16 * mt + l15) * 512 + s * 64 + g * 16));

  // ---- masks hoisted as floats (attention wave = (d=wm, half=wn))
  float maskf0[4], maskf1[4];
  {
    const int* ML = (const int*)(smem + 78336);
    const int mk0 = ML[32 * wm + l15];
    const int mk1 = ML[32 * wm + 16 + l15];
#pragma unroll
    for (int rr = 0; rr < 4; ++rr) {
      const int mq = ML[32 * wm + 16 * wn + 4 * g + rr];
      maskf0[rr] = (mq < mk0) ? -1000.f : 0.f;
      maskf1[rr] = (mq < mk1) ? -1000.f : 0.f;
    }
  }
  // ones B-fragment for softmax row-sum via MFMA
  bf16x8 ones;
#pragma unroll
  for (int j = 0; j < 8; ++j) ones[j] = (short)0x3F80;

  __syncthreads();   // A-image reads complete -> region becomes weight tiles

  const int wub   = (t >> 6) << 10;              // wave-uniform chunk base
  const int bb    = g * 512 + l15 * 16;          // frag B read base
  const int mbase = wn ? 16384 : 0;              // q strips vs k strips
  const int voff  = 32768 + (wn ? 256 : 0);      // v0 vs v1 tile
  const char* gblk = (const char*)wqf + t * 16;  // per-lane global base

  // ---- prologue prefetch: k,v tiles of head 0 (chunks 2..5)
#pragma unroll
  for (int j = 2; j < 6; ++j)
    gload16(gblk + j * 8192, smem + j * 8192 + wub);

#pragma unroll 1
  for (int h = 0; h < 8; ++h) {
    // ---- stage q tile of head h (chunks 0,1); k,v already in flight
    {
      const char* gh = gblk + (size_t)h * 49152;
      gload16(gh, smem + wub);
      gload16(gh + 8192, smem + 8192 + wub);
    }
    __syncthreads();   // drains vmcnt: all 6 chunks of B(h) landed

    // ---- GEMM: this wave's 3 n-tiles x 2 m-tiles (each B read feeds 2 MFMA)
    float4v a0[2], a1[2], av[2];
#pragma unroll
    for (int mt = 0; mt < 2; ++mt) {
      a0[mt] = (float4v){0.f, 0.f, 0.f, 0.f};
      a1[mt] = a0[mt];
      av[mt] = a0[mt];
    }
#pragma unroll
    for (int s = 0; s < 8; ++s) {
      const bf16x8 b0 = *reinterpret_cast<const bf16x8*>(smem + bb + s * 2048 + mbase);
      const bf16x8 b1 = *reinterpret_cast<const bf16x8*>(smem + bb + s * 2048 + mbase + 256);
      const bf16x8 bv = *reinterpret_cast<const bf16x8*>(smem + bb + s * 2048 + voff);
#pragma unroll
      for (int mt = 0; mt < 2; ++mt) {
        a0[mt] = mfma16(areg[mt][s], b0, a0[mt]);
        a1[mt] = mfma16(areg[mt][s], b1, a1[mt]);
        av[mt] = mfma16(areg[mt][s], bv, av[mt]);
      }
    }

    // ---- epilogue: bias + RoPE -> QKq/QKk ; v -> VT
    {
      const float bb0 = bqkv[wn * 256 + h * 32 + l15];
      const float bb1 = bqkv[wn * 256 + h * 32 + 16 + l15];
      const float bvv = bqkv[512 + h * 32 + 16 * wn + l15];
      const float* Fp = (const float*)(smem + 80384) + (h * 16 + l15) * 3;
      const float F0 = Fp[0], F1 = Fp[1], F2 = Fp[2];
      char* qkdst = smem + (wn ? 59392 : 49152);
      char* vdst  = smem + 69632 + (l15 + 16 * wn) * 272;
#pragma unroll
      for (int mt = 0; mt < 2; ++mt)
#pragma unroll
        for (int rr = 0; rr < 4; ++rr) {
          const int row  = 32 * wm + 16 * mt + 4 * g + rr;
          const int prow = ((row & 3) << 5) | (row >> 2);
          const float* xp = (const float*)(smem + 78848) + row * 3;
          const float th = xp[0] * F0 + xp[1] * F1 + xp[2] * F2;
          const float fr = __builtin_amdgcn_fractf(th);
          const float sn = __builtin_amdgcn_sinf(fr);
          const float cs = __builtin_amdgcn_cosf(fr);
          const float e0 = a0[mt][rr] + bb0;
          const float e1 = a1[mt][rr] + bb1;
          *reinterpret_cast<unsigned*>(qkdst + prow * 80 + 4 * l15) =
              cvtpk(e0 * cs - e1 * sn, e1 * cs + e0 * sn);
          const int kk = row >> 2, dd = row & 3;
          const int cpos = (kk < 16) ? (kk << 1) : (((kk - 16) << 1) | 1);
          *reinterpret_cast<unsigned short*>(vdst + (dd * 32 + cpos) * 2) =
              f2bf(av[mt][rr] + bvv);
        }
    }
    __syncthreads();   // QK/VT visible; all GEMM B-reads of head h complete

    // ---- prefetch k,v tiles of head h+1 (write [16384,49152): disjoint from
    //      PL [0,10240), QKq/QKk, VT — safe to be in flight during attention)
    if (h < 7) {
      const char* gn = gblk + (size_t)(h + 1) * 49152;
#pragma unroll
      for (int j = 2; j < 6; ++j)
        gload16(gn + j * 8192, smem + j * 8192 + wub);
    }

    // ---- attention: wave = (group wm, half wn), head h
    {
      const bf16x8 aq = *reinterpret_cast<const bf16x8*>(
          smem + 49152 + (32 * wm + 16 * wn + l15) * 80 + 16 * g);
      const bf16x8 bk0 = *reinterpret_cast<const bf16x8*>(
          smem + 59392 + (32 * wm + l15) * 80 + 16 * g);
      const bf16x8 bk1 = *reinterpret_cast<const bf16x8*>(
          smem + 59392 + (32 * wm + 16 + l15) * 80 + 16 * g);
      float4v s0 = {0.f,0.f,0.f,0.f}, s1 = s0;
      s0 = mfma16(aq, bk0, s0);
      s1 = mfma16(aq, bk1, s1);

      char* plw = smem + w * 1280;     // aliases dead q weight tile
#pragma unroll
      for (int rr = 0; rr < 4; ++rr) {
        // scores are O(0.2) -> exp without max-subtraction is safe
        const float p0 = __expf(s0[rr] * SCALE_ + maskf0[rr]);
        const float p1 = __expf(s1[rr] * SCALE_ + maskf1[rr]);
        *reinterpret_cast<unsigned*>(plw + (4 * g + rr) * 80 + 4 * l15) =
            pack2bf(p0, p1);
      }
      const bf16x8 ap = *reinterpret_cast<const bf16x8*>(plw + l15 * 80 + 16 * g);
      const bf16x8 bv0 = *reinterpret_cast<const bf16x8*>(
          smem + 69632 + l15 * 272 + wm * 64 + 16 * g);
      const bf16x8 bv1 = *reinterpret_cast<const bf16x8*>(
          smem + 69632 + (l15 + 16) * 272 + wm * 64 + 16 * g);
      float4v o0 = {0.f,0.f,0.f,0.f}, o1 = o0, osum = o0;
      osum = mfma16(ap, ones, osum);
      o0   = mfma16(ap, bv0, o0);
      o1   = mfma16(ap, bv1, o1);

      char* ob = (char*)aout + (size_t)b * 131072 + h * 64;
#pragma unroll
      for (int rr = 0; rr < 4; ++rr) {
        const float rs = __builtin_amdgcn_rcpf(osum[rr]);
        const int n_local = (16 * wn + 4 * g + rr) * 4 + wm;
        *reinterpret_cast<unsigned*>(ob + n_local * 512 + 4 * l15) =
            pack2bf(o0[rr] * rs, o1[rr] * rs);
      }
    }
    __syncthreads();   // PL/QK/VT reads done; q region reusable next iter
  }
}

// ------------------------------- K2: proj ----------------------------------
// A restage r7-verbatim (swz both sides); B via frag blob + global_load_lds.
#define K2_LDS_BYTES 81920

__global__ __launch_bounds__(512, 4) void k_proj(
    const unsigned short* ain,                       // d_out bf16 (aliases out!)
    const unsigned short* __restrict__ wpf,
    const float* __restrict__ bproj,
    float* out) {
  extern __shared__ char smem2[];
  const int b = blockIdx.x, t = threadIdx.x;
  const int lane = t & 63, w = t >> 6;
  const int g = lane >> 4, l15 = lane & 15;
  const int wub = (t >> 6) << 10;
  const char* gblk = (const char*)wpf + t * 16;

  {
    const char* abase = (const char*)ain + (size_t)b * 131072;
    bf16x8 stg[8];
#pragma unroll
    for (int i = 0; i < 8; ++i)
      stg[i] = *reinterpret_cast<const bf16x8*>(abase + i * 8192 + t * 16);
#pragma unroll
    for (int i = 0; i < 8; ++i)
      *reinterpret_cast<bf16x8*>(smem2 + swz(i * 8192 + t * 16)) = stg[i];
  }
  // issue B(0) staging (linear frag blob)
  gload16(gblk, smem2 + 65536 + wub);
  gload16(gblk + 8192, smem2 + 65536 + 8192 + wub);
  __syncthreads();   // A image + B(0) ready

  bf16x8 areg[8];
#pragma unroll
  for (int s = 0; s < 8; ++s)
    areg[s] = *reinterpret_cast<const bf16x8*>(
        smem2 + swz((16 * w + l15) * 512 + s * 64 + g * 16));

#pragma unroll 1
  for (int p = 0; p < 8; ++p) {
    float4v acc0 = {0.f,0.f,0.f,0.f}, acc1 = acc0;
#pragma unroll
    for (int s = 0; s < 8; ++s) {
      const bf16x8 b0 = *reinterpret_cast<const bf16x8*>(
          smem2 + 65536 + s * 2048 + g * 512 + l15 * 16);
      const bf16x8 b1 = *reinterpret_cast<const bf16x8*>(
          smem2 + 65536 + s * 2048 + g * 512 + l15 * 16 + 256);
      acc0 = mfma16(areg[s], b0, acc0);
      acc1 = mfma16(areg[s], b1, acc1);
    }
    __syncthreads();   // all waves done reading B(p)
    if (p < 7) {       // issue B(p+1); latency hides under the f32 stores
      const char* gn = gblk + (size_t)(p + 1) * 16384;
      gload16(gn, smem2 + 65536 + wub);
      gload16(gn + 8192, smem2 + 65536 + 8192 + wub);
    }
    const int col0 = 32 * p + l15, col1 = col0 + 16;
    const float bb0 = bproj[col0], bb1 = bproj[col1];
#pragma unroll
    for (int rr = 0; rr < 4; ++rr) {
      const int row = 16 * w + 4 * g + rr;
      out[((size_t)b * 128 + row) * 256 + col0] = acc0[rr] + bb0;
      out[((size_t)b * 128 + row) * 256 + col1] = acc1[rr] + bb1;
    }
    __syncthreads();   // drains vmcnt -> B(p+1) landed
  }
}

// ----------------------------- launch --------------------------------------
extern "C" void kernel_launch(void* const* d_in, const int* in_sizes, int n_in,
                              void* d_out, int out_size, void* d_ws, size_t ws_size,
                              hipStream_t stream) {
  const float* data  = (const float*)d_in[0];
  const float* xyz   = (const float*)d_in[1];
  const int*   depth = (const int*)d_in[2];
  const float* wqkv  = (const float*)d_in[3];
  const float* bqkv  = (const float*)d_in[4];
  const float* wproj = (const float*)d_in[5];
  const float* bproj = (const float*)d_in[6];
  const float* freqs = (const float*)d_in[7];

  unsigned short* wqkv_f  = (unsigned short*)d_ws;          // frag-ordered blob
  unsigned short* wproj_f = wqkv_f + 768 * 256;             // frag-ordered blob

  (void)hipFuncSetAttribute(reinterpret_cast<const void*>(k_fused),
                            hipFuncAttributeMaxDynamicSharedMemorySize, K1_LDS_BYTES);
  (void)hipFuncSetAttribute(reinterpret_cast<const void*>(k_proj),
                            hipFuncAttributeMaxDynamicSharedMemorySize, K2_LDS_BYTES);

  k_prep<<<dim3(1024), dim3(256), 0, stream>>>(wqkv, wproj, wqkv_f, wproj_f);
  k_fused<<<dim3(3125), dim3(512), K1_LDS_BYTES, stream>>>(
      data, xyz, depth, bqkv, freqs, wqkv_f, (unsigned short*)d_out);
  k_proj<<<dim3(3125), dim3(512), K2_LDS_BYTES, stream>>>(
      (const unsigned short*)d_out, wproj_f, bproj, (float*)d_out);
}

// Round 11
// 444.457 us; speedup vs baseline: 1.4320x; 1.2054x over previous
//
#include <hip/hip_runtime.h>
#include <math.h>

// ---------------------------------------------------------------------------
// OctreeAttention fused, round 11 = r7 structure (16-row waves, areg=32 VGPR,
// 2 blocks/CU — best green point, 343us) + the r9/r10-green staging upgrade:
//   - weight staging via __builtin_amdgcn_global_load_lds width=16 on the
//     frag-ordered blob (linear copy, zero staging VGPRs/VALU)
//   - q tile issued at loop top; k/v tiles of head h+1 issued after the
//     epilogue barrier so latency hides under attention (disjoint regions)
// Micro-grafts verified green in r8: freqs pre-scaled by 1/2pi + fractf,
// v_cvt_pk_bf16_f32 for the q/k epilogue store.
// Post-mortem r8-r10: areg[2][8]=64 regs (2:1 MFMA:ds_read split) cannot
// coexist with 2 blocks/CU (spill at (512,4), 1 block/CU at (512,2)) — the
// occupancy loss outweighs the halved LDS reads. r=16 waves it is.
// k_prep / k_proj verbatim from green r10.
// ---------------------------------------------------------------------------

typedef float  float4v __attribute__((ext_vector_type(4)));
typedef short  bf16x8  __attribute__((ext_vector_type(8)));   // 8 bf16 = 4 VGPR
typedef unsigned short us4 __attribute__((ext_vector_type(4)));

#define SCALE_ 0.17677669529663687f   // 32^-0.5
#define INV2PI 0.15915494309189535f

__device__ __forceinline__ unsigned short f2bf(float x) {
  union { float f; unsigned u; } v; v.f = x;
  unsigned r = v.u + 0x7FFFu + ((v.u >> 16) & 1u);   // RNE
  return (unsigned short)(r >> 16);
}
__device__ __forceinline__ unsigned pack2bf(float lo, float hi) {
  return (unsigned)f2bf(lo) | ((unsigned)f2bf(hi) << 16);
}
// single-instruction pack: src0 -> bits[15:0], src1 -> bits[31:16]
__device__ __forceinline__ unsigned cvtpk(float lo, float hi) {
  unsigned r;
  asm("v_cvt_pk_bf16_f32 %0, %1, %2" : "=v"(r) : "v"(lo), "v"(hi));
  return r;
}
__device__ __forceinline__ float4v mfma16(bf16x8 a, bf16x8 b, float4v c) {
  return __builtin_amdgcn_mfma_f32_16x16x32_bf16(a, b, c, 0, 0, 0);
}
// XOR swizzle within 512B rows (A images only; B paths are linear)
__device__ __forceinline__ int swz(int off) {
  return off ^ (((off >> 9) & 7) << 4);
}
// async global->LDS, 16B per lane; lds dst is wave-uniform base (+lane*16 by HW)
__device__ __forceinline__ void gload16(const void* gsrc, char* ldst) {
  __builtin_amdgcn_global_load_lds(
      (const __attribute__((address_space(1))) unsigned int*)gsrc,
      (__attribute__((address_space(3))) unsigned int*)ldst, 16, 0, 0);
}

// ------------------------------- K0: weights -------------------------------
// wqf: fragment-ordered bf16 blob. element(h,mat,s,g,col,e) =
//   h*24576 + mat*8192 + s*1024 + g*256 + col*8 + e
//   holds Wqkv[ci][co], ci = s*32+g*8+e, co = mat*256+h*32+col.
// wpf: fragment-ordered wproj blob. element(p,s,g,col,e) =
//   p*8192 + s*1024 + g*256 + col*8 + e
//   holds Wproj[perm(cpos)][co], cpos = s*32+g*8+e, co = p*32+col,
//   perm(cpos)=hh*32+f, hh=cpos>>5, ww=cpos&31, f=(ww&1)?16+(ww>>1):(ww>>1)
__global__ __launch_bounds__(256) void k_prep(const float* __restrict__ wqkv,
                                              const float* __restrict__ wproj,
                                              unsigned short* __restrict__ wqf,
                                              unsigned short* __restrict__ wpf) {
  int tid = blockIdx.x * 256 + threadIdx.x;
  if (tid < 768 * 256) {
    int h  = tid / 24576;
    int r  = tid - h * 24576;
    int mat = r >> 13;
    int r2  = r & 8191;
    int s = r2 >> 10, g = (r2 >> 8) & 3, col = (r2 >> 3) & 31, e = r2 & 7;
    int ci = s * 32 + g * 8 + e;
    int co = mat * 256 + h * 32 + col;
    wqf[tid] = f2bf(wqkv[ci * 768 + co]);
  } else {
    int u = tid - 768 * 256;
    int p = u >> 13;
    int r2 = u & 8191;
    int s = r2 >> 10, g = (r2 >> 8) & 3, col = (r2 >> 3) & 31, e = r2 & 7;
    int cpos = s * 32 + g * 8 + e;
    int hh = cpos >> 5, ww = cpos & 31;
    int f = (ww & 1) ? 16 + (ww >> 1) : (ww >> 1);
    wpf[u] = f2bf(wproj[(hh * 32 + f) * 256 + p * 32 + col]);
  }
}

// ------------------------------- K1: fused ---------------------------------
// LDS (bytes):
//   B_s   @ 0      49152  3 frag-order weight tiles (q,k,v) 16KB each
//                         (PL aliases [0,10240) during attention; A-image
//                          (swz) aliases [0,65536) in the prologue)
//   QKq   @ 49152  10240  q [128 prow][80B] feature-pair interleaved
//   QKk   @ 59392  10240  k   "
//   VT    @ 69632   8704  V^T [32 f][272B], keys cpos-interleaved
//   ML    @ 78336    512  depths (prow order)
//   XYZ   @ 78848   1536  xyz f32 (row order)
//   F_s   @ 80384   1536  freqs f32, pre-scaled by 1/2pi
#define K1_LDS_BYTES 81920

__global__ __launch_bounds__(512, 4) void k_fused(
    const float* __restrict__ data, const float* __restrict__ xyz,
    const int* __restrict__ depth, const float* __restrict__ bqkv,
    const float* __restrict__ freqs, const unsigned short* __restrict__ wqf,
    unsigned short* __restrict__ aout /* d_out viewed as bf16 */) {
  extern __shared__ char smem[];
  const int b    = blockIdx.x;
  const int t    = threadIdx.x;
  const int lane = t & 63;
  const int w    = t >> 6;         // wave 0..7: owns point rows [16w,16w+16)
  const int g    = lane >> 4;      // 0..3
  const int l15  = lane & 15;
  const int d    = w >> 1;         // attention group
  const int half = w & 1;          // 16-row half within group

  // ---- stage small tables
  if (t < 128) ((int*)(smem + 78336))[t] =
      depth[b * 128 + ((t & 31) << 2) + (t >> 5)];          // prow order
  if (t < 384) ((float*)(smem + 78848))[t] = xyz[(size_t)b * 384 + t];
  if (t < 384) ((float*)(smem + 80384))[t] = freqs[t] * INV2PI;

  // ---- A restage: coalesced f32 loads -> swizzled bf16 [128][512B]
  {
    const float* dbase = data + (size_t)b * 32768;
#pragma unroll
    for (int i = 0; i < 16; ++i) {
      const int fidx = i * 512 + t;
      const float4v v4 = *reinterpret_cast<const float4v*>(dbase + fidx * 4);
      us4 pk;
      pk.x = f2bf(v4.x); pk.y = f2bf(v4.y); pk.z = f2bf(v4.z); pk.w = f2bf(v4.w);
      *reinterpret_cast<us4*>(smem + swz(fidx * 8)) = pk;
    }
  }
  __syncthreads();

  // ---- A fragments -> registers (16 rows/wave, reused for all 8 heads)
  bf16x8 areg[8];
#pragma unroll
  for (int s = 0; s < 8; ++s)
    areg[s] = *reinterpret_cast<const bf16x8*>(
        smem + swz((16 * w + l15) * 512 + s * 64 + g * 16));

  // ---- masks hoisted as floats (attention wave = (d, half))
  float maskf0[4], maskf1[4];
  {
    const int* ML = (const int*)(smem + 78336);
    const int mk0 = ML[32 * d + l15];
    const int mk1 = ML[32 * d + 16 + l15];
#pragma unroll
    for (int rr = 0; rr < 4; ++rr) {
      const int mq = ML[32 * d + 16 * half + 4 * g + rr];
      maskf0[rr] = (mq < mk0) ? -1000.f : 0.f;
      maskf1[rr] = (mq < mk1) ? -1000.f : 0.f;
    }
  }
  // ones B-fragment for softmax row-sum via MFMA
  bf16x8 ones;
#pragma unroll
  for (int j = 0; j < 8; ++j) ones[j] = (short)0x3F80;

  __syncthreads();   // A-image reads complete -> region becomes weight tiles

  const int wub    = (t >> 6) << 10;             // wave-uniform chunk base
  const int bb     = g * 512 + l15 * 16;         // frag B read base
  const char* gblk = (const char*)wqf + t * 16;  // per-lane global base

  // ---- prologue prefetch: k,v tiles of head 0 (chunks 2..5)
#pragma unroll
  for (int j = 2; j < 6; ++j)
    gload16(gblk + j * 8192, smem + j * 8192 + wub);

#pragma unroll 1
  for (int h = 0; h < 8; ++h) {
    // ---- stage q tile of head h (chunks 0,1); k,v already in flight
    {
      const char* gh = gblk + (size_t)h * 49152;
      gload16(gh, smem + wub);
      gload16(gh + 8192, smem + 8192 + wub);
    }
    __syncthreads();   // drains vmcnt: all 6 chunks of B(h) landed

    // ---- GEMM q & k (share RoPE theta); B reads are base+immediate
    {
      float4v q0a = {0.f,0.f,0.f,0.f}, q1a = q0a, k0a = q0a, k1a = q0a;
#pragma unroll
      for (int s = 0; s < 8; ++s) {
        const bf16x8 bq0 = *reinterpret_cast<const bf16x8*>(smem + bb + s * 2048);
        const bf16x8 bq1 = *reinterpret_cast<const bf16x8*>(smem + bb + s * 2048 + 256);
        const bf16x8 bk0 = *reinterpret_cast<const bf16x8*>(smem + bb + s * 2048 + 16384);
        const bf16x8 bk1 = *reinterpret_cast<const bf16x8*>(smem + bb + s * 2048 + 16384 + 256);
        q0a = mfma16(areg[s], bq0, q0a);
        q1a = mfma16(areg[s], bq1, q1a);
        k0a = mfma16(areg[s], bk0, k0a);
        k1a = mfma16(areg[s], bk1, k1a);
      }
      const float bq0v = bqkv[h * 32 + l15];
      const float bq1v = bqkv[h * 32 + 16 + l15];
      const float bk0v = bqkv[256 + h * 32 + l15];
      const float bk1v = bqkv[256 + h * 32 + 16 + l15];
      const float* Fp = (const float*)(smem + 80384) + (h * 16 + l15) * 3;
      const float F0 = Fp[0], F1 = Fp[1], F2 = Fp[2];
#pragma unroll
      for (int rr = 0; rr < 4; ++rr) {
        const int row  = 16 * w + 4 * g + rr;
        const int prow = ((row & 3) << 5) | (row >> 2);
        const float* xp = (const float*)(smem + 78848) + row * 3;
        const float th = xp[0] * F0 + xp[1] * F1 + xp[2] * F2;
        const float fr = __builtin_amdgcn_fractf(th);
        const float sn = __builtin_amdgcn_sinf(fr);
        const float cs = __builtin_amdgcn_cosf(fr);
        const float q0 = q0a[rr] + bq0v, q1 = q1a[rr] + bq1v;
        const float k0 = k0a[rr] + bk0v, k1 = k1a[rr] + bk1v;
        *reinterpret_cast<unsigned*>(smem + 49152 + prow * 80 + 4 * l15) =
            cvtpk(q0 * cs - q1 * sn, q1 * cs + q0 * sn);
        *reinterpret_cast<unsigned*>(smem + 59392 + prow * 80 + 4 * l15) =
            cvtpk(k0 * cs - k1 * sn, k1 * cs + k0 * sn);
      }
    }
    // ---- GEMM v + epilogue (VT: transposed, keys cpos-interleaved)
    {
      float4v v0a = {0.f,0.f,0.f,0.f}, v1a = v0a;
#pragma unroll
      for (int s = 0; s < 8; ++s) {
        const bf16x8 bv0 = *reinterpret_cast<const bf16x8*>(smem + bb + s * 2048 + 32768);
        const bf16x8 bv1 = *reinterpret_cast<const bf16x8*>(smem + bb + s * 2048 + 32768 + 256);
        v0a = mfma16(areg[s], bv0, v0a);
        v1a = mfma16(areg[s], bv1, v1a);
      }
      const float bv0v = bqkv[512 + h * 32 + l15];
      const float bv1v = bqkv[512 + h * 32 + 16 + l15];
#pragma unroll
      for (int rr = 0; rr < 4; ++rr) {
        const int row = 16 * w + 4 * g + rr;
        const int kk = row >> 2, dd = row & 3;
        const int cpos = (kk < 16) ? (kk << 1) : (((kk - 16) << 1) | 1);
        *reinterpret_cast<unsigned short*>(
            smem + 69632 + l15 * 272 + (dd * 32 + cpos) * 2) = f2bf(v0a[rr] + bv0v);
        *reinterpret_cast<unsigned short*>(
            smem + 69632 + (l15 + 16) * 272 + (dd * 32 + cpos) * 2) = f2bf(v1a[rr] + bv1v);
      }
    }
    __syncthreads();   // QK/VT visible; all GEMM B-reads of head h complete

    // ---- prefetch k,v tiles of head h+1 (write [16384,49152): disjoint from
    //      PL [0,10240), QKq/QKk, VT — safe to be in flight during attention)
    if (h < 7) {
      const char* gn = gblk + (size_t)(h + 1) * 49152;
#pragma unroll
      for (int j = 2; j < 6; ++j)
        gload16(gn + j * 8192, smem + j * 8192 + wub);
    }

    // ---- attention: wave = (group d, half), head h
    {
      const bf16x8 aq = *reinterpret_cast<const bf16x8*>(
          smem + 49152 + (32 * d + 16 * half + l15) * 80 + 16 * g);
      const bf16x8 bk0 = *reinterpret_cast<const bf16x8*>(
          smem + 59392 + (32 * d + l15) * 80 + 16 * g);
      const bf16x8 bk1 = *reinterpret_cast<const bf16x8*>(
          smem + 59392 + (32 * d + 16 + l15) * 80 + 16 * g);
      float4v s0 = {0.f,0.f,0.f,0.f}, s1 = s0;
      s0 = mfma16(aq, bk0, s0);
      s1 = mfma16(aq, bk1, s1);

      char* plw = smem + w * 1280;     // aliases dead q weight tile
#pragma unroll
      for (int rr = 0; rr < 4; ++rr) {
        // scores are O(0.2) -> exp without max-subtraction is safe
        const float p0 = __expf(s0[rr] * SCALE_ + maskf0[rr]);
        const float p1 = __expf(s1[rr] * SCALE_ + maskf1[rr]);
        *reinterpret_cast<unsigned*>(plw + (4 * g + rr) * 80 + 4 * l15) =
            pack2bf(p0, p1);
      }
      const bf16x8 ap = *reinterpret_cast<const bf16x8*>(plw + l15 * 80 + 16 * g);
      const bf16x8 bv0 = *reinterpret_cast<const bf16x8*>(
          smem + 69632 + l15 * 272 + d * 64 + 16 * g);
      const bf16x8 bv1 = *reinterpret_cast<const bf16x8*>(
          smem + 69632 + (l15 + 16) * 272 + d * 64 + 16 * g);
      float4v o0 = {0.f,0.f,0.f,0.f}, o1 = o0, osum = o0;
      osum = mfma16(ap, ones, osum);
      o0   = mfma16(ap, bv0, o0);
      o1   = mfma16(ap, bv1, o1);

      char* ob = (char*)aout + (size_t)b * 131072 + h * 64;
#pragma unroll
      for (int rr = 0; rr < 4; ++rr) {
        const float rs = __builtin_amdgcn_rcpf(osum[rr]);
        const int n_local = (16 * half + 4 * g + rr) * 4 + d;
        *reinterpret_cast<unsigned*>(ob + n_local * 512 + 4 * l15) =
            pack2bf(o0[rr] * rs, o1[rr] * rs);
      }
    }
    __syncthreads();   // PL/QK/VT reads done; q region reusable next iter
  }
}

// ------------------------------- K2: proj ----------------------------------
// verbatim from green r10: A restage (swz both sides); B via frag blob +
// global_load_lds; B(p+1) issued before the f32 stores.
#define K2_LDS_BYTES 81920

__global__ __launch_bounds__(512, 4) void k_proj(
    const unsigned short* ain,                       // d_out bf16 (aliases out!)
    const unsigned short* __restrict__ wpf,
    const float* __restrict__ bproj,
    float* out) {
  extern __shared__ char smem2[];
  const int b = blockIdx.x, t = threadIdx.x;
  const int lane = t & 63, w = t >> 6;
  const int g = lane >> 4, l15 = lane & 15;
  const int wub = (t >> 6) << 10;
  const char* gblk = (const char*)wpf + t * 16;

  {
    const char* abase = (const char*)ain + (size_t)b * 131072;
    bf16x8 stg[8];
#pragma unroll
    for (int i = 0; i < 8; ++i)
      stg[i] = *reinterpret_cast<const bf16x8*>(abase + i * 8192 + t * 16);
#pragma unroll
    for (int i = 0; i < 8; ++i)
      *reinterpret_cast<bf16x8*>(smem2 + swz(i * 8192 + t * 16)) = stg[i];
  }
  // issue B(0) staging (linear frag blob)
  gload16(gblk, smem2 + 65536 + wub);
  gload16(gblk + 8192, smem2 + 65536 + 8192 + wub);
  __syncthreads();   // A image + B(0) ready

  bf16x8 areg[8];
#pragma unroll
  for (int s = 0; s < 8; ++s)
    areg[s] = *reinterpret_cast<const bf16x8*>(
        smem2 + swz((16 * w + l15) * 512 + s * 64 + g * 16));

#pragma unroll 1
  for (int p = 0; p < 8; ++p) {
    float4v acc0 = {0.f,0.f,0.f,0.f}, acc1 = acc0;
#pragma unroll
    for (int s = 0; s < 8; ++s) {
      const bf16x8 b0 = *reinterpret_cast<const bf16x8*>(
          smem2 + 65536 + s * 2048 + g * 512 + l15 * 16);
      const bf16x8 b1 = *reinterpret_cast<const bf16x8*>(
          smem2 + 65536 + s * 2048 + g * 512 + l15 * 16 + 256);
      acc0 = mfma16(areg[s], b0, acc0);
      acc1 = mfma16(areg[s], b1, acc1);
    }
    __syncthreads();   // all waves done reading B(p)
    if (p < 7) {       // issue B(p+1); latency hides under the f32 stores
      const char* gn = gblk + (size_t)(p + 1) * 16384;
      gload16(gn, smem2 + 65536 + wub);
      gload16(gn + 8192, smem2 + 65536 + 8192 + wub);
    }
    const int col0 = 32 * p + l15, col1 = col0 + 16;
    const float bb0 = bproj[col0], bb1 = bproj[col1];
#pragma unroll
    for (int rr = 0; rr < 4; ++rr) {
      const int row = 16 * w + 4 * g + rr;
      out[((size_t)b * 128 + row) * 256 + col0] = acc0[rr] + bb0;
      out[((size_t)b * 128 + row) * 256 + col1] = acc1[rr] + bb1;
    }
    __syncthreads();   // drains vmcnt -> B(p+1) landed
  }
}

// ----------------------------- launch --------------------------------------
extern "C" void kernel_launch(void* const* d_in, const int* in_sizes, int n_in,
                              void* d_out, int out_size, void* d_ws, size_t ws_size,
                              hipStream_t stream) {
  const float* data  = (const float*)d_in[0];
  const float* xyz   = (const float*)d_in[1];
  const int*   depth = (const int*)d_in[2];
  const float* wqkv  = (const float*)d_in[3];
  const float* bqkv  = (const float*)d_in[4];
  const float* wproj = (const float*)d_in[5];
  const float* bproj = (const float*)d_in[6];
  const float* freqs = (const float*)d_in[7];

  unsigned short* wqkv_f  = (unsigned short*)d_ws;          // frag-ordered blob
  unsigned short* wproj_f = wqkv_f + 768 * 256;             // frag-ordered blob

  (void)hipFuncSetAttribute(reinterpret_cast<const void*>(k_fused),
                            hipFuncAttributeMaxDynamicSharedMemorySize, K1_LDS_BYTES);
  (void)hipFuncSetAttribute(reinterpret_cast<const void*>(k_proj),
                            hipFuncAttributeMaxDynamicSharedMemorySize, K2_LDS_BYTES);

  k_prep<<<dim3(1024), dim3(256), 0, stream>>>(wqkv, wproj, wqkv_f, wproj_f);
  k_fused<<<dim3(3125), dim3(512), K1_LDS_BYTES, stream>>>(
      data, xyz, depth, bqkv, freqs, wqkv_f, (unsigned short*)d_out);
  k_proj<<<dim3(3125), dim3(512), K2_LDS_BYTES, stream>>>(
      (const unsigned short*)d_out, wproj_f, bproj, (float*)d_out);
}